// Round 4
// baseline (701.667 us; speedup 1.0000x reference)
//
#include <hip/hip_runtime.h>
#include <math.h>

// Problem constants (fixed by setup_inputs)
#define BD   1024            // batch B
#define LW   80              // walk length L
#define AA   76              // anchors A = L - w + 1, w = 5
#define NEGS 4               // negatives per anchor
#define D    128             // embed dim
#define PAIRS (BD * AA)      // 77824 (b,a) pairs
#define NNEG  (PAIRS * NEGS) // 311296 neg incidences
#define NLOGIT ((size_t)PAIRS * 8)  // 622592

// Bucketing: bucket = idx >> 10  -> 1e6 rows / 1024 => <=1024 buckets,
// each covering a 1024-row (512 KB) address window. Processing records
// bucket-major confines concurrent HBM gathers to narrow spans (DRAM row
// + TLB locality) instead of fully-random over 512 MB.
#define NBUCKET 1024
#define BSHIFT  10
#define CPAD    16           // pad counters to separate 64B lines

// ws layout
#define CNT_OFF   0                       // int cnt[1024*16]   (64 KB)
#define CUR_OFF   (NBUCKET * CPAD)       // int cur[1024*16]   (64 KB)
#define REC_OFF_BYTES  (1u << 18)        // int2 rec[311296]   (2.5 MB)
#define PART_OFF_BYTES (1u << 22)        // float partials
#define POS_BLOCKS 4864                  // 4864*16 waves = 77824 pairs
#define NEG_BLOCKS 19456                 // 19456*16 waves = 311296 records
#define NPART (POS_BLOCKS + NEG_BLOCKS)  // 24320

__device__ __forceinline__ float softplus(float x) {
    return fmaxf(x, 0.0f) + log1pf(__expf(-fabsf(x)));
}

// ---- bucketing machinery -------------------------------------------------

__global__ __launch_bounds__(1024) void k_zero(int* __restrict__ wsi) {
    const int i = blockIdx.x * 1024 + threadIdx.x;   // grid 32 -> 32768 ints
    wsi[i] = 0;                                       // zeroes cnt + cur
}

__global__ __launch_bounds__(1024) void k_hist(
    const int* __restrict__ neg, int* __restrict__ cnt)
{
    __shared__ int h[NBUCKET];
    const int tid = threadIdx.x;
    h[tid] = 0;
    __syncthreads();
    const int beg = blockIdx.x * (NNEG / 64);        // 64 blocks x 4864 items
    const int end = beg + (NNEG / 64);
    for (int i = beg + tid; i < end; i += 1024)
        atomicAdd(&h[neg[i] >> BSHIFT], 1);
    __syncthreads();
    if (h[tid]) atomicAdd(&cnt[tid * CPAD], h[tid]);
}

__global__ __launch_bounds__(1024) void k_scan(
    const int* __restrict__ cnt, int* __restrict__ cur)
{
    __shared__ int s[NBUCKET];
    const int tid = threadIdx.x;
    const int c = cnt[tid * CPAD];
    s[tid] = c;
    __syncthreads();
    for (int off = 1; off < NBUCKET; off <<= 1) {
        int t = (tid >= off) ? s[tid - off] : 0;
        __syncthreads();
        s[tid] += t;
        __syncthreads();
    }
    cur[tid * CPAD] = s[tid] - c;                    // exclusive prefix
}

__global__ __launch_bounds__(1024) void k_scatter(
    const int* __restrict__ neg, int* __restrict__ cur, int2* __restrict__ rec)
{
    const int i = blockIdx.x * 1024 + threadIdx.x;   // grid 304 -> 311296 exact
    const int idx = neg[i];
    const int pos = atomicAdd(&cur[(idx >> BSHIFT) * CPAD], 1);
    rec[pos] = make_int2(idx, i >> 2);               // (row index, pair id)
}

// ---- compute -------------------------------------------------------------

// One pair per wave: anchor + 4 pos rows (random gathers, 82k unique rows;
// runs FIRST so these rows are L3-warm for k_neg's anchor reads).
__global__ __launch_bounds__(1024) void k_pos(
    const int* __restrict__ walk, const float* __restrict__ embed,
    float* __restrict__ part)
{
    __shared__ float s[16];
    const int tid  = threadIdx.x;
    const int lane = tid & 63;
    const int wave = __builtin_amdgcn_readfirstlane(tid >> 6);
    const int p    = blockIdx.x * 16 + wave;         // < 77824 always
    const int b    = p / AA;
    const int a    = p - b * AA;

    const int* wr = walk + b * LW + a;               // wave-uniform -> s_load
    const int anc = wr[0], t0 = wr[1], t1 = wr[2], t2 = wr[3], t3 = wr[4];

    const float* erow = embed + (size_t)(lane * 2);
    const float2 ea = *(const float2*)(erow + (size_t)anc * D);
    const float2 e0 = *(const float2*)(erow + (size_t)t0  * D);
    const float2 e1 = *(const float2*)(erow + (size_t)t1  * D);
    const float2 e2 = *(const float2*)(erow + (size_t)t2  * D);
    const float2 e3 = *(const float2*)(erow + (size_t)t3  * D);

    float p0 = fmaf(ea.x, e0.x, ea.y * e0.y);
    float p1 = fmaf(ea.x, e1.x, ea.y * e1.y);
    float p2 = fmaf(ea.x, e2.x, ea.y * e2.y);
    float p3 = fmaf(ea.x, e3.x, ea.y * e3.y);

    // reduce-scatter: lane ends with full logit (lane&3), replicated 16x
    const bool h1 = lane & 1, h2 = lane & 2;
    float q0 = (h1 ? p1 : p0) + __shfl_xor(h1 ? p0 : p1, 1);
    float q1 = (h1 ? p3 : p2) + __shfl_xor(h1 ? p2 : p3, 1);
    float dv = (h2 ? q1 : q0) + __shfl_xor(h2 ? q0 : q1, 2);
    dv += __shfl_xor(dv, 4);
    dv += __shfl_xor(dv, 8);
    dv += __shfl_xor(dv, 16);
    dv += __shfl_xor(dv, 32);

    float v = softplus(-dv);                         // pos logits: softplus(-x)
    v += __shfl_xor(v, 1);                           // sum the 4 distinct logits
    v += __shfl_xor(v, 2);                           // (crosses logit ids only)

    if (lane == 0) s[wave] = v;
    __syncthreads();
    if (tid == 0) {
        float t = 0.f;
        #pragma unroll
        for (int i = 0; i < 16; ++i) t += s[i];
        part[blockIdx.x] = t;
    }
}

// One neg record per wave, processed bucket-major: target gathers are
// confined to ~512KB windows; anchor rows come from L3 (warmed by k_pos).
__global__ __launch_bounds__(1024) void k_neg(
    const int* __restrict__ walk, const float* __restrict__ embed,
    const int2* __restrict__ rec, float* __restrict__ part)
{
    __shared__ float s[16];
    const int tid  = threadIdx.x;
    const int lane = tid & 63;
    const int wave = __builtin_amdgcn_readfirstlane(tid >> 6);
    const int rid  = blockIdx.x * 16 + wave;         // < 311296 always

    const int2 rc = rec[rid];                        // wave-uniform
    const int idx = __builtin_amdgcn_readfirstlane(rc.x);
    const int p   = __builtin_amdgcn_readfirstlane(rc.y);
    const int b   = p / AA;
    const int a   = p - b * AA;
    const int anc = walk[b * LW + a];                // uniform -> s_load

    const float* erow = embed + (size_t)(lane * 2);
    const float2 et = *(const float2*)(erow + (size_t)idx * D);
    const float2 ea = *(const float2*)(erow + (size_t)anc * D);

    float dv = fmaf(et.x, ea.x, et.y * ea.y);
    dv += __shfl_xor(dv, 1);
    dv += __shfl_xor(dv, 2);
    dv += __shfl_xor(dv, 4);
    dv += __shfl_xor(dv, 8);
    dv += __shfl_xor(dv, 16);
    dv += __shfl_xor(dv, 32);

    if (lane == 0) s[wave] = softplus(dv);           // neg logits: softplus(+x)
    __syncthreads();
    if (tid == 0) {
        float t = 0.f;
        #pragma unroll
        for (int i = 0; i < 16; ++i) t += s[i];
        part[POS_BLOCKS + blockIdx.x] = t;
    }
}

__global__ __launch_bounds__(1024) void k_reduce(
    const float* __restrict__ part, float* __restrict__ out)
{
    __shared__ float s[16];
    const int tid = threadIdx.x;
    float sum = 0.f;
    for (int i = tid; i < NPART; i += 1024) sum += part[i];
    #pragma unroll
    for (int m = 1; m < 64; m <<= 1) sum += __shfl_xor(sum, m);
    const int wave = tid >> 6, lane = tid & 63;
    if (lane == 0) s[wave] = sum;
    __syncthreads();
    if (tid == 0) {
        float acc = 0.f;
        #pragma unroll
        for (int i = 0; i < 16; ++i) acc += s[i];
        out[0] = acc * (1.0f / (float)NLOGIT);
    }
}

extern "C" void kernel_launch(void* const* d_in, const int* in_sizes, int n_in,
                              void* d_out, int out_size, void* d_ws, size_t ws_size,
                              hipStream_t stream) {
    const int*   walk  = (const int*)d_in[0];
    const int*   neg   = (const int*)d_in[1];
    const float* embed = (const float*)d_in[2];

    int*   wsi  = (int*)d_ws;
    int*   cnt  = wsi + CNT_OFF;
    int*   cur  = wsi + CUR_OFF;
    int2*  rec  = (int2*)((char*)d_ws + REC_OFF_BYTES);
    float* part = (float*)((char*)d_ws + PART_OFF_BYTES);
    float* out  = (float*)d_out;

    k_zero   <<<32,   1024, 0, stream>>>(wsi);
    k_hist   <<<64,   1024, 0, stream>>>(neg, cnt);
    k_scan   <<<1,    1024, 0, stream>>>(cnt, cur);
    k_scatter<<<304,  1024, 0, stream>>>(neg, cur, rec);
    k_pos    <<<POS_BLOCKS, 1024, 0, stream>>>(walk, embed, part);
    k_neg    <<<NEG_BLOCKS, 1024, 0, stream>>>(walk, embed, rec, part);
    k_reduce <<<1,    1024, 0, stream>>>(part, out);
}